// Round 1
// baseline (185.833 us; speedup 1.0000x reference)
//
#include <hip/hip_runtime.h>
#include <hip/hip_fp16.h>
#include <math.h>

#define NN 100000
#define NE 1600000
#define FIN 50
#define NC 16
#define TILE_NODES 32

#define NPB 128                       // nodes per bucket (was 256)
#define NB  ((NN + NPB - 1) / NPB)    // 782 buckets
#define CAP 2304                      // slots per bucket (mean 2048 + 5.7 sigma)
#define NBLK_PART 1024                // was 256: 4x place-role parallelism
#define EPB ((NE + NBLK_PART - 1) / NBLK_PART)   // 1563 edges / partition block
#define KEDGE ((EPB + 255) / 256)                // 7 register-cached edges/thread
#define NBLK_LIN 1024

// ---------------------------------------------------------------------------
// Fused front-end. Blocks [0, NBLK_PART): placement of edges into
// fixed-capacity bucket regions (latency-bound fabric scatter — now 1024
// blocks so the scatter tail runs at full occupancy instead of 4 waves/CU).
// Blocks [NBLK_PART, NBLK_PART+NBLK_LIN): y_l = x@W_l^T (f16) and
// self = x@W_r^T (f32). Grid = 2048 blocks of 256 = fully co-resident
// (8 blocks/CU), so the two roles overlap everywhere: cost = max, not sum.
// ---------------------------------------------------------------------------
__global__ __launch_bounds__(256) void fused_front(
    const float* __restrict__ x,
    const float* __restrict__ W_l,
    const float* __restrict__ W_r,
    const int* __restrict__ ei,       // [2, NE]
    int* __restrict__ gcur_s,         // [NB*16] cursors (zeroed)
    unsigned int* __restrict__ buf,   // [NB*CAP]
    __half2* __restrict__ y_l,        // [NN*8]
    float* __restrict__ self_out)     // [NN*NC]
{
    __shared__ __align__(16) char smem[12800];
    const int tid = threadIdx.x;

    if (blockIdx.x < NBLK_PART) {
        // ---- place role ----
        int* h   = (int*)smem;        // [NB]
        int* cur = h + NB;            // [NB]
        for (int i = tid; i < NB; i += 256) h[i] = 0;

        const int e0 = blockIdx.x * EPB;
        const int e1 = min(e0 + EPB, NE);

        // register-cache this thread's edges: ei read ONCE (statically
        // indexed unroll so er[] stays in VGPRs, not scratch)
        int2 er[KEDGE];
#pragma unroll
        for (int k = 0; k < KEDGE; ++k) {
            const int e = e0 + tid + (k << 8);
            if (e < e1) { er[k].x = ei[e]; er[k].y = ei[NE + e]; }
        }
        __syncthreads();

        // per-bucket histogram (LDS int atomics)
#pragma unroll
        for (int k = 0; k < KEDGE; ++k) {
            const int e = e0 + tid + (k << 8);
            if (e < e1) atomicAdd(&h[((unsigned)er[k].y) >> 7], 1);
        }
        __syncthreads();

        // one global cursor reservation per nonempty bucket
        for (int b = tid; b < NB; b += 256)
            cur[b] = h[b] ? atomicAdd(&gcur_s[b * 16], h[b]) : 0;
        __syncthreads();

        // scatter from registers (1 LDS atomic + 1 global 4B write / edge)
#pragma unroll
        for (int k = 0; k < KEDGE; ++k) {
            const int e = e0 + tid + (k << 8);
            if (e < e1) {
                const int s = er[k].x;
                const int t = er[k].y;
                const int bkt = ((unsigned)t) >> 7;
                const int pos = atomicAdd(&cur[bkt], 1);
                if (pos < CAP)
                    buf[(size_t)bkt * CAP + pos] =
                        (unsigned)s | ((unsigned)(t & 127) << 17);
            }
        }
    } else {
        // ---- lin role ----
        float* sWl = (float*)smem;            // [NC*FIN]
        float* sWr = sWl + NC * FIN;          // [NC*FIN]
        float* sx  = sWr + NC * FIN;          // [TILE_NODES*FIN]

        for (int i = tid; i < NC * FIN; i += 256) {
            sWl[i] = W_l[i];
            sWr[i] = W_r[i];
        }

        const int bidx = blockIdx.x - NBLK_PART;
        const int ntiles = (NN + TILE_NODES - 1) / TILE_NODES;
        const int ln = tid >> 3;
        const int cp = tid & 7;

        for (int tile = bidx; tile < ntiles; tile += NBLK_LIN) {
            __syncthreads();
            const int node0 = tile * TILE_NODES;
            for (int i = tid; i < TILE_NODES * FIN; i += 256) {
                int n = node0 + i / FIN;
                sx[i] = (n < NN) ? x[n * FIN + (i % FIN)] : 0.0f;
            }
            __syncthreads();

            const int n = node0 + ln;
            if (n >= NN) continue;

            const float* xr = &sx[ln * FIN];
            const float* w0 = &sWl[(2 * cp) * FIN];
            const float* w1 = w0 + FIN;
            const float* u0 = &sWr[(2 * cp) * FIN];
            const float* u1 = u0 + FIN;

            float a0 = 0.f, a1 = 0.f, r0 = 0.f, r1 = 0.f;
#pragma unroll
            for (int k = 0; k < FIN; ++k) {
                float xv = xr[k];
                a0 = fmaf(xv, w0[k], a0);
                a1 = fmaf(xv, w1[k], a1);
                r0 = fmaf(xv, u0[k], r0);
                r1 = fmaf(xv, u1[k], r1);
            }
            y_l[n * 8 + cp] = __floats2half2_rn(a0, a1);
            ((float2*)self_out)[n * 8 + cp] = make_float2(r0, r1);
        }
    }
}

// ---------------------------------------------------------------------------
// Aggregation: one 512-thread block per 128-node bucket (782 blocks -> 4
// blocks/CU co-resident, single round, balanced; was 391x1024 = 2/CU with a
// 1.5-round straggler tail). In-LDS counting sort by local target, 128-wide
// scan, contention-free register segment-reduce (tid = tl*4+q, quad covers
// 16 classes via uint2 loads), fused mean/bias/self/log_softmax epilogue.
// ---------------------------------------------------------------------------
#define KAGG ((CAP + 511) / 512)      // 5 register-cached edges/thread

__global__ __launch_bounds__(512) void agg_kernel(
    const int* __restrict__ gcur_s,
    const unsigned int* __restrict__ buf,
    const uint2* __restrict__ y2,     // y_l as uint2[NN*4]
    const float* __restrict__ b_l,
    float* __restrict__ logp,
    float* __restrict__ outv)         // self (f32) on entry, final out on exit
{
    __shared__ unsigned slist[CAP];   // 9.2 KB
    __shared__ int lcnt[NPB];
    __shared__ int scur[NPB];
    __shared__ int sstart[NPB];
    __shared__ int wsum[4];
    __shared__ float sb[NC];

    const int tid = threadIdx.x;
    if (tid < NPB) lcnt[tid] = 0;
    if (tid < NC) sb[tid] = b_l[tid];
    __syncthreads();

    const int b = blockIdx.x;
    int cnt = gcur_s[b * 16];
    if (cnt > CAP) cnt = CAP;
    const size_t base = (size_t)b * CAP;

    // register-cache this block's bucket slice: buf read ONCE
    unsigned ev[KAGG];
#pragma unroll
    for (int k = 0; k < KAGG; ++k) {
        const int i = tid + (k << 9);
        if (i < cnt) ev[k] = buf[base + i];
    }

    // pass 1: per-local-node counts (1 LDS int atomic per edge)
#pragma unroll
    for (int k = 0; k < KAGG; ++k) {
        const int i = tid + (k << 9);
        if (i < cnt) atomicAdd(&lcnt[ev[k] >> 17], 1);
    }
    __syncthreads();

    // pass 2: 128-wide exclusive scan (2 waves scan 64 each, then fixup)
    int own = 0, incl = 0;
    if (tid < NPB) {
        own = lcnt[tid];
        incl = own;
#pragma unroll
        for (int off = 1; off < 64; off <<= 1) {
            int t = __shfl_up(incl, off, 64);
            if ((tid & 63) >= off) incl += t;
        }
        if ((tid & 63) == 63) wsum[tid >> 6] = incl;
    }
    __syncthreads();
    if (tid < NPB) {
        const int st = ((tid >= 64) ? wsum[0] : 0) + incl - own;
        sstart[tid] = st;
        scur[tid]   = st;
    }
    __syncthreads();

    // pass 3: scatter src ids into sorted slots (1 atomic + 1 write per edge)
#pragma unroll
    for (int k = 0; k < KAGG; ++k) {
        const int i = tid + (k << 9);
        if (i < cnt) {
            const unsigned v = ev[k];
            const int pos = atomicAdd(&scur[v >> 17], 1);
            slist[pos] = v & 0x1FFFF;
        }
    }
    __syncthreads();

    // pass 4: segment reduce, registers only. tid = tl*4 + q.
    const int tl = tid >> 2;
    const int q  = tid & 3;
    const int n  = b * NPB + tl;
    if (n >= NN) return;

    const int seg0 = sstart[tl];
    const int deg  = lcnt[tl];
    const int seg1 = seg0 + deg;

    float a0 = 0.f, a1 = 0.f, a2 = 0.f, a3 = 0.f;
    int i = seg0;
    for (; i + 2 <= seg1; i += 2) {
        int sA = slist[i];
        int sB = slist[i + 1];
        uint2 qa = y2[sA * 4 + q];
        uint2 qb = y2[sB * 4 + q];
        float2 fa = __half22float2(__builtin_bit_cast(__half2, qa.x));
        float2 fb = __half22float2(__builtin_bit_cast(__half2, qa.y));
        float2 fc = __half22float2(__builtin_bit_cast(__half2, qb.x));
        float2 fd = __half22float2(__builtin_bit_cast(__half2, qb.y));
        a0 += fa.x + fc.x;
        a1 += fa.y + fc.y;
        a2 += fb.x + fd.x;
        a3 += fb.y + fd.y;
    }
    if (i < seg1) {
        uint2 qa = y2[slist[i] * 4 + q];
        float2 fa = __half22float2(__builtin_bit_cast(__half2, qa.x));
        float2 fb = __half22float2(__builtin_bit_cast(__half2, qa.y));
        a0 += fa.x; a1 += fa.y; a2 += fb.x; a3 += fb.y;
    }

    // pass 5: fused epilogue, width-4 shfl reductions
    const float4 sf = ((const float4*)(outv + (size_t)n * NC))[q];
    float inv = 1.0f / fmaxf((float)deg, 1.0f);
    float v0 = a0 * inv + sb[4 * q + 0] + sf.x;
    float v1 = a1 * inv + sb[4 * q + 1] + sf.y;
    float v2 = a2 * inv + sb[4 * q + 2] + sf.z;
    float v3 = a3 * inv + sb[4 * q + 3] + sf.w;

    float m = fmaxf(fmaxf(v0, v1), fmaxf(v2, v3));
    m = fmaxf(m, __shfl_xor(m, 1, 4));
    m = fmaxf(m, __shfl_xor(m, 2, 4));
    float es = expf(v0 - m) + expf(v1 - m) + expf(v2 - m) + expf(v3 - m);
    es += __shfl_xor(es, 1, 4);
    es += __shfl_xor(es, 2, 4);
    float lse = m + logf(es);

    ((float4*)(outv + (size_t)n * NC))[q] = make_float4(v0, v1, v2, v3);
    ((float4*)(logp + (size_t)n * NC))[q] =
        make_float4(v0 - lse, v1 - lse, v2 - lse, v3 - lse);
}

extern "C" void kernel_launch(void* const* d_in, const int* in_sizes, int n_in,
                              void* d_out, int out_size, void* d_ws, size_t ws_size,
                              hipStream_t stream) {
    const float* x   = (const float*)d_in[0];
    const int*   ei  = (const int*)d_in[1];
    const float* W_l = (const float*)d_in[2];
    const float* b_l = (const float*)d_in[3];
    const float* W_r = (const float*)d_in[4];

    float* logp = (float*)d_out;                    // [NN*NC]
    float* outv = (float*)d_out + (size_t)NN * NC;  // [NN*NC], self scratch

    // ws: y_l half2[NN*8] (3.2MB) | buf u32[NB*CAP] (7.2MB) | gcur_s[NB*16] (50KB)
    __half2* y_l  = (__half2*)d_ws;
    unsigned* buf = (unsigned*)(y_l + (size_t)NN * 8);
    int* gcur_s   = (int*)(buf + (size_t)NB * CAP);

    hipMemsetAsync(gcur_s, 0, (size_t)NB * 16 * sizeof(int), stream);

    fused_front<<<NBLK_PART + NBLK_LIN, 256, 0, stream>>>(
        x, W_l, W_r, ei, gcur_s, buf, y_l, outv);
    agg_kernel<<<NB, 512, 0, stream>>>(gcur_s, buf, (const uint2*)y_l, b_l, logp, outv);
}

// Round 3
// 130.456 us; speedup vs baseline: 1.4245x; 1.4245x over previous
//
#include <hip/hip_runtime.h>
#include <hip/hip_fp16.h>
#include <math.h>

#define NN 100000
#define NE 1600000
#define FIN 50
#define NC 16
#define TILE_NODES 32

#define NPB 256                       // nodes per bucket
#define NB  ((NN + NPB - 1) / NPB)    // 391 buckets
#define CAP 4608                      // slots per bucket (mean 4092 + 8 sigma)
#define NBLK_PART 256
#define EPB (NE / NBLK_PART)          // 6250 edges / partition block (exact)
#define NBLK_LIN 512

// ---------------------------------------------------------------------------
// Fused front-end. Blocks [0, NBLK_PART): placement of edges into
// fixed-capacity bucket regions. Round-1 lesson: scattered 4B stores write
// ~1 cache line per edge (WRITE_SIZE 72MB); the fix is an in-LDS counting
// sort by bucket, then a COALESCED output pass — consecutive lanes write
// consecutive addresses within each ~16-edge bucket run, so a wave's 64
// stores span ~4-5 lines instead of 64. Blocks [NBLK_PART, +NBLK_LIN):
// y_l = x@W_l^T (f16) and self = x@W_r^T (f32). Grid = 768 blocks of 256 at
// 43.8KB LDS = 3 blocks/CU, fully co-resident -> roles overlap, cost = max.
// ---------------------------------------------------------------------------
__global__ __launch_bounds__(256) void fused_front(
    const float* __restrict__ x,
    const float* __restrict__ W_l,
    const float* __restrict__ W_r,
    const int* __restrict__ ei,       // [2, NE]
    int* __restrict__ gcur_s,         // [NB*16] cursors (zeroed)
    unsigned int* __restrict__ buf,   // [NB*CAP]
    __half2* __restrict__ y_l,        // [NN*8]
    float* __restrict__ self_out)     // [NN*NC]
{
    // place: h[NB] lstart[NB] lcur[NB] gbase[NB] (6256B) | slist[EPB] (25000B)
    //        | bid u16[EPB] (12500B)  = 43756B.  lin: 12.8KB (reuses front).
    __shared__ __align__(16) char smem[43776];
    __shared__ int wsum[4];
    const int tid = threadIdx.x;

    if (blockIdx.x < NBLK_PART) {
        // ---- place role ----
        int* h      = (int*)smem;                 // [NB] histogram
        int* lstart = h + NB;                     // [NB] local sorted start
        int* lcur   = lstart + NB;                // [NB] scatter cursor
        int* gbase  = lcur + NB;                  // [NB] global reserved base
        unsigned* slist = (unsigned*)(gbase + NB);            // [EPB]
        unsigned short* bid = (unsigned short*)(slist + EPB); // [EPB]

        for (int i = tid; i < NB; i += 256) h[i] = 0;
        __syncthreads();

        const int e0 = blockIdx.x * EPB;          // EPB divides NE exactly

        // pass 1: histogram over buckets (LDS int atomics, targets only)
        for (int i = tid; i < EPB; i += 256)
            atomicAdd(&h[((unsigned)ei[NE + e0 + i]) >> 8], 1);
        __syncthreads();

        // pass 2: exclusive scan of h[0..NB) -> lstart. Thread t owns
        // buckets {2t, 2t+1}; 256-wide scan of pair-sums (wave scan + fixup).
        {
            const int i0 = 2 * tid, i1 = 2 * tid + 1;
            const int h0 = (i0 < NB) ? h[i0] : 0;
            const int h1 = (i1 < NB) ? h[i1] : 0;
            const int own = h0 + h1;
            int incl = own;
#pragma unroll
            for (int off = 1; off < 64; off <<= 1) {
                int t = __shfl_up(incl, off, 64);
                if ((tid & 63) >= off) incl += t;
            }
            if ((tid & 63) == 63) wsum[tid >> 6] = incl;
            __syncthreads();
            const int w = tid >> 6;
            int pfx = 0;
            if (w > 0) pfx += wsum[0];
            if (w > 1) pfx += wsum[1];
            if (w > 2) pfx += wsum[2];
            const int excl = pfx + incl - own;
            if (i0 < NB) { lstart[i0] = excl; lcur[i0] = excl; }
            if (i1 < NB) { lstart[i1] = excl + h0; lcur[i1] = excl + h0; }
        }
        __syncthreads();

        // pass 3: one global cursor reservation per nonempty bucket
        for (int b = tid; b < NB; b += 256)
            gbase[b] = h[b] ? atomicAdd(&gcur_s[b * 16], h[b]) : 0;

        // pass 4: counting-sort scatter into LDS (1 LDS atomic + 2 LDS
        // writes per edge — cheap vs. a scattered global line each)
        for (int i = tid; i < EPB; i += 256) {
            const int s = ei[e0 + i];
            const int t = ei[NE + e0 + i];
            const int b = ((unsigned)t) >> 8;
            const int pos = atomicAdd(&lcur[b], 1);
            slist[pos] = (unsigned)s | ((unsigned)(t & 255) << 17);
            bid[pos] = (unsigned short)b;
        }
        __syncthreads();

        // pass 5: coalesced output — consecutive i => consecutive global
        // addresses within each bucket run (~16 edges = 64B)
        for (int i = tid; i < EPB; i += 256) {
            const unsigned v = slist[i];
            const int b = bid[i];
            const int goff = gbase[b] + (i - lstart[b]);
            if (goff < CAP)
                buf[(size_t)b * CAP + goff] = v;
        }
    } else {
        // ---- lin role ----
        float* sWl = (float*)smem;            // [NC*FIN]
        float* sWr = sWl + NC * FIN;          // [NC*FIN]
        float* sx  = sWr + NC * FIN;          // [TILE_NODES*FIN]

        for (int i = tid; i < NC * FIN; i += 256) {
            sWl[i] = W_l[i];
            sWr[i] = W_r[i];
        }

        const int bidx = blockIdx.x - NBLK_PART;
        const int ntiles = (NN + TILE_NODES - 1) / TILE_NODES;
        const int ln = tid >> 3;
        const int cp = tid & 7;

        for (int tile = bidx; tile < ntiles; tile += NBLK_LIN) {
            __syncthreads();
            const int node0 = tile * TILE_NODES;
            for (int i = tid; i < TILE_NODES * FIN; i += 256) {
                int n = node0 + i / FIN;
                sx[i] = (n < NN) ? x[n * FIN + (i % FIN)] : 0.0f;
            }
            __syncthreads();

            const int n = node0 + ln;
            if (n >= NN) continue;

            const float* xr = &sx[ln * FIN];
            const float* w0 = &sWl[(2 * cp) * FIN];
            const float* w1 = w0 + FIN;
            const float* u0 = &sWr[(2 * cp) * FIN];
            const float* u1 = u0 + FIN;

            float a0 = 0.f, a1 = 0.f, r0 = 0.f, r1 = 0.f;
#pragma unroll
            for (int k = 0; k < FIN; ++k) {
                float xv = xr[k];
                a0 = fmaf(xv, w0[k], a0);
                a1 = fmaf(xv, w1[k], a1);
                r0 = fmaf(xv, u0[k], r0);
                r1 = fmaf(xv, u1[k], r1);
            }
            y_l[n * 8 + cp] = __floats2half2_rn(a0, a1);
            ((float2*)self_out)[n * 8 + cp] = make_float2(r0, r1);
        }
    }
}

// ---------------------------------------------------------------------------
// Aggregation (round-0 proven config): one 1024-thread block per bucket
// (256 nodes). In-LDS counting sort by local target, 256-wide scan,
// contention-free register segment-reduce (tid = tl*4+q, quad covers 16
// classes via uint2 loads), fused mean/bias/self/log_softmax epilogue.
// ---------------------------------------------------------------------------
__global__ __launch_bounds__(1024) void agg_kernel(
    const int* __restrict__ gcur_s,
    const unsigned int* __restrict__ buf,
    const uint2* __restrict__ y2,     // y_l as uint2[NN*4]
    const float* __restrict__ b_l,
    float* __restrict__ logp,
    float* __restrict__ outv)         // self (f32) on entry, final out on exit
{
    __shared__ unsigned slist[CAP];   // 18.4 KB
    __shared__ int lcnt[NPB];
    __shared__ int scur[NPB];
    __shared__ int sstart[NPB];
    __shared__ int wsum[4];
    __shared__ float sb[NC];

    const int tid = threadIdx.x;
    if (tid < NPB) lcnt[tid] = 0;
    if (tid < NC) sb[tid] = b_l[tid];
    __syncthreads();

    const int b = blockIdx.x;
    int cnt = gcur_s[b * 16];
    if (cnt > CAP) cnt = CAP;
    const size_t base = (size_t)b * CAP;

    // pass 1: per-local-node counts (1 LDS int atomic per edge)
    for (int i = tid; i < cnt; i += 1024)
        atomicAdd(&lcnt[buf[base + i] >> 17], 1);
    __syncthreads();

    // pass 2: 256-wide exclusive scan (4 waves scan 64 each, then fixup)
    int own = 0, incl = 0;
    if (tid < NPB) {
        own = lcnt[tid];
        incl = own;
#pragma unroll
        for (int off = 1; off < 64; off <<= 1) {
            int t = __shfl_up(incl, off, 64);
            if ((tid & 63) >= off) incl += t;
        }
        if ((tid & 63) == 63) wsum[tid >> 6] = incl;
    }
    __syncthreads();
    if (tid < NPB) {
        const int w = tid >> 6;
        int pfx = 0;
        if (w > 0) pfx += wsum[0];
        if (w > 1) pfx += wsum[1];
        if (w > 2) pfx += wsum[2];
        const int st = pfx + incl - own;
        sstart[tid] = st;
        scur[tid]   = st;
    }
    __syncthreads();

    // pass 3: scatter src ids into sorted slots (1 atomic + 1 write per edge)
    for (int i = tid; i < cnt; i += 1024) {
        unsigned v = buf[base + i];
        int pos = atomicAdd(&scur[v >> 17], 1);
        slist[pos] = v & 0x1FFFF;
    }
    __syncthreads();

    // pass 4: segment reduce, registers only. tid = tl*4 + q.
    const int tl = tid >> 2;
    const int q  = tid & 3;
    const int n  = b * NPB + tl;
    if (n >= NN) return;

    const int seg0 = sstart[tl];
    const int deg  = lcnt[tl];
    const int seg1 = seg0 + deg;

    float a0 = 0.f, a1 = 0.f, a2 = 0.f, a3 = 0.f;
    int i = seg0;
    for (; i + 2 <= seg1; i += 2) {
        int sA = slist[i];
        int sB = slist[i + 1];
        uint2 qa = y2[sA * 4 + q];
        uint2 qb = y2[sB * 4 + q];
        float2 fa = __half22float2(__builtin_bit_cast(__half2, qa.x));
        float2 fb = __half22float2(__builtin_bit_cast(__half2, qa.y));
        float2 fc = __half22float2(__builtin_bit_cast(__half2, qb.x));
        float2 fd = __half22float2(__builtin_bit_cast(__half2, qb.y));
        a0 += fa.x + fc.x;
        a1 += fa.y + fc.y;
        a2 += fb.x + fd.x;
        a3 += fb.y + fd.y;
    }
    if (i < seg1) {
        uint2 qa = y2[slist[i] * 4 + q];
        float2 fa = __half22float2(__builtin_bit_cast(__half2, qa.x));
        float2 fb = __half22float2(__builtin_bit_cast(__half2, qa.y));
        a0 += fa.x; a1 += fa.y; a2 += fb.x; a3 += fb.y;
    }

    // pass 5: fused epilogue, width-4 shfl reductions
    const float4 sf = ((const float4*)(outv + (size_t)n * NC))[q];
    float inv = 1.0f / fmaxf((float)deg, 1.0f);
    float v0 = a0 * inv + sb[4 * q + 0] + sf.x;
    float v1 = a1 * inv + sb[4 * q + 1] + sf.y;
    float v2 = a2 * inv + sb[4 * q + 2] + sf.z;
    float v3 = a3 * inv + sb[4 * q + 3] + sf.w;

    float m = fmaxf(fmaxf(v0, v1), fmaxf(v2, v3));
    m = fmaxf(m, __shfl_xor(m, 1, 4));
    m = fmaxf(m, __shfl_xor(m, 2, 4));
    float es = expf(v0 - m) + expf(v1 - m) + expf(v2 - m) + expf(v3 - m);
    es += __shfl_xor(es, 1, 4);
    es += __shfl_xor(es, 2, 4);
    float lse = m + logf(es);

    ((float4*)(outv + (size_t)n * NC))[q] = make_float4(v0, v1, v2, v3);
    ((float4*)(logp + (size_t)n * NC))[q] =
        make_float4(v0 - lse, v1 - lse, v2 - lse, v3 - lse);
}

extern "C" void kernel_launch(void* const* d_in, const int* in_sizes, int n_in,
                              void* d_out, int out_size, void* d_ws, size_t ws_size,
                              hipStream_t stream) {
    const float* x   = (const float*)d_in[0];
    const int*   ei  = (const int*)d_in[1];
    const float* W_l = (const float*)d_in[2];
    const float* b_l = (const float*)d_in[3];
    const float* W_r = (const float*)d_in[4];

    float* logp = (float*)d_out;                    // [NN*NC]
    float* outv = (float*)d_out + (size_t)NN * NC;  // [NN*NC], self scratch

    // ws: y_l half2[NN*8] (3.2MB) | buf u32[NB*CAP] (7.2MB) | gcur_s[NB*16] (25KB)
    __half2* y_l  = (__half2*)d_ws;
    unsigned* buf = (unsigned*)(y_l + (size_t)NN * 8);
    int* gcur_s   = (int*)(buf + (size_t)NB * CAP);

    hipMemsetAsync(gcur_s, 0, (size_t)NB * 16 * sizeof(int), stream);

    fused_front<<<NBLK_PART + NBLK_LIN, 256, 0, stream>>>(
        x, W_l, W_r, ei, gcur_s, buf, y_l, outv);
    agg_kernel<<<NB, 1024, 0, stream>>>(gcur_s, buf, (const uint2*)y_l, b_l, logp, outv);
}